// Round 1
// baseline (992.200 us; speedup 1.0000x reference)
//
#include <hip/hip_runtime.h>
#include <hip/hip_bf16.h>
#include <cstdint>
#include <cstddef>

// ---------- types ----------
typedef __bf16 bf16_t;
typedef __bf16 bf16x8 __attribute__((ext_vector_type(8)));
typedef float  f32x4  __attribute__((ext_vector_type(4)));

#define DIM    1024
#define NCOEF  8
#define KTOT   (DIM + DIM * NCOEF)   // 9216
#define NKNOT  12
#define BATCH  8192
#define LN_EPS 1e-5f

// ---------- device helpers ----------
__device__ __forceinline__ float gelu_exact(float x) {
    return 0.5f * x * (1.0f + erff(x * 0.70710678118654752440f));
}

// Cox–de Boor recursion, SPLINE_ORDER=3, 12 knots -> 8 bases. Mirrors reference.
__device__ __forceinline__ void spline_bases(float x, const float* __restrict__ g,
                                             float* __restrict__ out8) {
    float gg[NKNOT];
#pragma unroll
    for (int i = 0; i < NKNOT; i++) gg[i] = g[i];
    float B[11];
#pragma unroll
    for (int i = 0; i < 11; i++)
        B[i] = (x >= gg[i] && x < gg[i + 1]) ? 1.0f : 0.0f;
#pragma unroll
    for (int k = 1; k <= 3; k++) {
#pragma unroll
        for (int i = 0; i < 11; i++) {
            if (i + k < 11) {
                float dl = gg[i + k] - gg[i];
                dl = (dl == 0.0f) ? 1.0f : dl;
                float t1 = (x - gg[i]) / dl;
                float t2 = (gg[i + k + 1] - x) / (gg[i + k + 1] - gg[i + 1]);
                B[i] = t1 * B[i] + t2 * B[i + 1];
            }
        }
    }
#pragma unroll
    for (int i = 0; i < NCOEF; i++) out8[i] = B[i];
}

__device__ __forceinline__ void write_act(bf16_t* __restrict__ arow, int col,
                                          float xv, const float* __restrict__ grid) {
    arow[col] = (bf16_t)gelu_exact(xv);
    float b8[NCOEF];
    spline_bases(xv, grid + col * NKNOT, b8);
    bf16x8 v;
#pragma unroll
    for (int c = 0; c < NCOEF; c++) v[c] = (bf16_t)b8[c];
    *(bf16x8*)(arow + DIM + col * NCOEF) = v;
}

// ---------- W pack: [base_w | spline_w] f32 -> bf16, K-interleaved ----------
// Wbuf row (layer*1024 + o), cols: [0,1024) = base_w[o][j]; [1024 + 8j + c] = spline_w[o][j][c]
__global__ void pack_w(const float* __restrict__ bw, const float* __restrict__ sw,
                       bf16_t* __restrict__ W) {
    int idx = blockIdx.x * 256 + threadIdx.x;      // 0 .. 2*1024*1024-1 -> (layer,o,j)
    bf16_t* wrow = W + (size_t)(idx >> 10) * KTOT;
    int j = idx & 1023;
    wrow[j] = (bf16_t)bw[idx];
    const float4* sp = (const float4*)(sw + (size_t)idx * NCOEF);
    float4 s0 = sp[0], s1 = sp[1];
    bf16x8 v;
    v[0] = (bf16_t)s0.x; v[1] = (bf16_t)s0.y; v[2] = (bf16_t)s0.z; v[3] = (bf16_t)s0.w;
    v[4] = (bf16_t)s1.x; v[5] = (bf16_t)s1.y; v[6] = (bf16_t)s1.z; v[7] = (bf16_t)s1.w;
    *(bf16x8*)(wrow + DIM + j * NCOEF) = v;
}

// ---------- activation build from raw x (layer 0) ----------
__global__ void act_build(const float* __restrict__ x, const float* __restrict__ grid,
                          bf16_t* __restrict__ Abuf) {
    int idx = blockIdx.x * 256 + threadIdx.x;      // slab-local b*1024 + j
    int b = idx >> 10, j = idx & 1023;
    write_act(Abuf + (size_t)b * KTOT, j, x[idx], grid);
}

// ---------- GEMM: C[M,1024] = A[M,9216](bf16) * B[1024,9216]^T, f32 out ----------
__device__ __forceinline__ void gl_lds16(const void* g, void* l) {
    __builtin_amdgcn_global_load_lds(
        (const __attribute__((address_space(1))) unsigned int*)(uintptr_t)g,
        (__attribute__((address_space(3))) unsigned int*)(uintptr_t)l, 16, 0, 0);
}

__global__ __launch_bounds__(256) void gemm_bt(const bf16_t* __restrict__ A,
                                               const bf16_t* __restrict__ B,
                                               float* __restrict__ C) {
    constexpr int K = KTOT, N = DIM;
    __shared__ __align__(16) bf16_t At[128 * 64];
    __shared__ __align__(16) bf16_t Bt[128 * 64];
    const int tid = threadIdx.x;
    const int l = tid & 63;
    const int w = tid >> 6;
    const int wm = w & 1, wn = w >> 1;
    const int bm = blockIdx.x >> 3, bn = blockIdx.x & 7;

    const bf16_t* Ag = A + (size_t)(bm * 128 + (tid >> 3)) * K + (tid & 7) * 8;
    const bf16_t* Bg = B + (size_t)(bn * 128 + (tid >> 3)) * K + (tid & 7) * 8;
    bf16_t* Al = At + tid * 8;   // per-lane dest == wave-uniform base + lane*16B
    bf16_t* Bl = Bt + tid * 8;

    f32x4 acc[4][4] = {};
    const bf16_t* Ar = At + (wm * 64 + (l & 15)) * 64 + (l >> 4) * 8;
    const bf16_t* Br = Bt + (wn * 64 + (l & 15)) * 64 + (l >> 4) * 8;

    for (int k0 = 0; k0 < K; k0 += 64) {
#pragma unroll
        for (int q = 0; q < 4; q++) {
            gl_lds16(Ag + (size_t)q * 32 * K + k0, Al + q * 2048);
            gl_lds16(Bg + (size_t)q * 32 * K + k0, Bl + q * 2048);
        }
        asm volatile("s_waitcnt vmcnt(0)" ::: "memory");
        __syncthreads();
#pragma unroll
        for (int kk = 0; kk < 2; kk++) {
            bf16x8 af[4], bfr[4];
#pragma unroll
            for (int i = 0; i < 4; i++) af[i] = *(const bf16x8*)(Ar + i * 16 * 64 + kk * 32);
#pragma unroll
            for (int j = 0; j < 4; j++) bfr[j] = *(const bf16x8*)(Br + j * 16 * 64 + kk * 32);
#pragma unroll
            for (int i = 0; i < 4; i++)
#pragma unroll
                for (int j = 0; j < 4; j++)
                    acc[i][j] = __builtin_amdgcn_mfma_f32_16x16x32_bf16(af[i], bfr[j], acc[i][j], 0, 0, 0);
        }
        __syncthreads();
    }

    const int r0 = bm * 128 + wm * 64 + (l >> 4) * 4;
    const int c0 = bn * 128 + wn * 64 + (l & 15);
#pragma unroll
    for (int i = 0; i < 4; i++)
#pragma unroll
        for (int j = 0; j < 4; j++)
#pragma unroll
            for (int r = 0; r < 4; r++)
                C[(size_t)(r0 + i * 16 + r) * N + c0 + j * 16] = acc[i][j][r];
}

// ---------- LayerNorm + PReLU -> next-layer activations (bf16) ----------
__global__ void ln_act(const float* __restrict__ h, const float* __restrict__ g_ln,
                       const float* __restrict__ b_ln, const float* __restrict__ pa,
                       const float* __restrict__ grid, bf16_t* __restrict__ Abuf) {
    const int row = blockIdx.x, tid = threadIdx.x;
    const int w = tid >> 6, l = tid & 63;
    f32x4 v = *(const f32x4*)(h + (size_t)row * DIM + tid * 4);
    float s = v[0] + v[1] + v[2] + v[3];
    float q = v[0] * v[0] + v[1] * v[1] + v[2] * v[2] + v[3] * v[3];
#pragma unroll
    for (int o = 32; o > 0; o >>= 1) { s += __shfl_xor(s, o); q += __shfl_xor(q, o); }
    __shared__ float rs[4], rq[4];
    if (l == 0) { rs[w] = s; rq[w] = q; }
    __syncthreads();
    s = rs[0] + rs[1] + rs[2] + rs[3];
    q = rq[0] + rq[1] + rq[2] + rq[3];
    float mean = s * (1.0f / DIM);
    float var = q * (1.0f / DIM) - mean * mean;
    float rstd = rsqrtf(var + LN_EPS);
    float a = pa[0];
    bf16_t* arow = Abuf + (size_t)row * KTOT;
#pragma unroll
    for (int c = 0; c < 4; c++) {
        int col = tid * 4 + c;
        float y = (v[c] - mean) * rstd * g_ln[col] + b_ln[col];
        y = (y >= 0.0f) ? y : a * y;
        write_act(arow, col, y, grid);
    }
}

// ---------- final LayerNorm + PReLU -> f32 out ----------
__global__ void ln_out(const float* __restrict__ h, const float* __restrict__ g_ln,
                       const float* __restrict__ b_ln, const float* __restrict__ pa,
                       float* __restrict__ out) {
    const int row = blockIdx.x, tid = threadIdx.x;
    const int w = tid >> 6, l = tid & 63;
    f32x4 v = *(const f32x4*)(h + (size_t)row * DIM + tid * 4);
    float s = v[0] + v[1] + v[2] + v[3];
    float q = v[0] * v[0] + v[1] * v[1] + v[2] * v[2] + v[3] * v[3];
#pragma unroll
    for (int o = 32; o > 0; o >>= 1) { s += __shfl_xor(s, o); q += __shfl_xor(q, o); }
    __shared__ float rs[4], rq[4];
    if (l == 0) { rs[w] = s; rq[w] = q; }
    __syncthreads();
    s = rs[0] + rs[1] + rs[2] + rs[3];
    q = rq[0] + rq[1] + rq[2] + rq[3];
    float mean = s * (1.0f / DIM);
    float var = q * (1.0f / DIM) - mean * mean;
    float rstd = rsqrtf(var + LN_EPS);
    float a = pa[0];
    f32x4 o4;
#pragma unroll
    for (int c = 0; c < 4; c++) {
        int col = tid * 4 + c;
        float y = (v[c] - mean) * rstd * g_ln[col] + b_ln[col];
        o4[c] = (y >= 0.0f) ? y : a * y;
    }
    *(f32x4*)(out + (size_t)row * DIM + tid * 4) = o4;
}

// ---------- launch ----------
extern "C" void kernel_launch(void* const* d_in, const int* in_sizes, int n_in,
                              void* d_out, int out_size, void* d_ws, size_t ws_size,
                              hipStream_t stream) {
    const float* x    = (const float*)d_in[0];
    const float* bw   = (const float*)d_in[1];
    const float* sw   = (const float*)d_in[2];
    const float* ln_g = (const float*)d_in[3];
    const float* ln_b = (const float*)d_in[4];
    const float* pa   = (const float*)d_in[5];
    const float* grid = (const float*)d_in[6];
    float* out = (float*)d_out;

    // Workspace: Wbuf (2 layers packed weights) + per-slab Abuf + h.
    const size_t wbytes = (size_t)2 * DIM * KTOT * sizeof(bf16_t);   // 37,748,736
    // pick largest slab R (multiple of 128, divides 8192) fitting ws
    int R = 8192;
    while (R > 128 && wbytes + (size_t)R * (KTOT * 2 + DIM * 4) > ws_size) R >>= 1;
    char* wsc = (char*)d_ws;
    bf16_t* Wbuf = (bf16_t*)wsc;
    bf16_t* Abuf = (bf16_t*)(wsc + wbytes);
    float*  hbuf = (float*)(wsc + wbytes + (size_t)R * KTOT * sizeof(bf16_t));

    pack_w<<<(2 * DIM * DIM) / 256, 256, 0, stream>>>(bw, sw, Wbuf);

    const int nslab = BATCH / R;
    for (int sidx = 0; sidx < nslab; sidx++) {
        const size_t row0 = (size_t)sidx * R;
        // layer 0
        act_build<<<R * DIM / 256, 256, 0, stream>>>(x + row0 * DIM, grid, Abuf);
        gemm_bt<<<(R / 128) * 8, 256, 0, stream>>>(Abuf, Wbuf, hbuf);
        ln_act<<<R, 256, 0, stream>>>(hbuf, ln_g, ln_b, pa, grid + DIM * NKNOT, Abuf);
        // layer 1
        gemm_bt<<<(R / 128) * 8, 256, 0, stream>>>(Abuf, Wbuf + (size_t)DIM * KTOT, hbuf);
        ln_out<<<R, 256, 0, stream>>>(hbuf, ln_g + DIM, ln_b + DIM, pa + 1, out + row0 * DIM);
    }
}

// Round 2
// 754.547 us; speedup vs baseline: 1.3150x; 1.3150x over previous
//
#include <hip/hip_runtime.h>
#include <hip/hip_bf16.h>
#include <cstdint>
#include <cstddef>

// ---------- types ----------
typedef __bf16 bf16_t;
typedef __bf16 bf16x8 __attribute__((ext_vector_type(8)));
typedef __bf16 bf16x4 __attribute__((ext_vector_type(4)));
typedef float  f32x4  __attribute__((ext_vector_type(4)));

#define DIM    1024
#define NCOEF  8
#define KTOT   (DIM + DIM * NCOEF)   // 9216
#define NKNOT  12
#define BATCH  8192
#define LN_EPS 1e-5f

// ---------- device helpers ----------
__device__ __forceinline__ float gelu_exact(float x) {
    return 0.5f * x * (1.0f + erff(x * 0.70710678118654752440f));
}

// ---------- W pack: [base_w | spline_w] f32 -> bf16, K-packed ----------
// Wbuf row (layer*1024 + o): [0,1024) = base_w[o][j]; [1024 + 8j + c] = spline_w[o][j][c]
__global__ void pack_w(const float* __restrict__ bw, const float* __restrict__ sw,
                       bf16_t* __restrict__ W) {
    int idx = blockIdx.x * 256 + threadIdx.x;      // (layer,o,j)
    bf16_t* wrow = W + (size_t)(idx >> 10) * KTOT;
    int j = idx & 1023;
    wrow[j] = (bf16_t)bw[idx];
    const float4* sp = (const float4*)(sw + (size_t)idx * NCOEF);
    float4 s0 = sp[0], s1 = sp[1];
    bf16x8 v;
    v[0] = (bf16_t)s0.x; v[1] = (bf16_t)s0.y; v[2] = (bf16_t)s0.z; v[3] = (bf16_t)s0.w;
    v[4] = (bf16_t)s1.x; v[5] = (bf16_t)s1.y; v[6] = (bf16_t)s1.z; v[7] = (bf16_t)s1.w;
    *(bf16x8*)(wrow + DIM + j * NCOEF) = v;
}

// ---------- gelu precompute: f32 x -> bf16 gelu(x) ----------
__global__ void prep_gelu(const float* __restrict__ x, bf16_t* __restrict__ g) {
    int idx = blockIdx.x * 256 + threadIdx.x;
    float4 v = ((const float4*)x)[idx];
    bf16x4 o;
    o[0] = (bf16_t)gelu_exact(v.x); o[1] = (bf16_t)gelu_exact(v.y);
    o[2] = (bf16_t)gelu_exact(v.z); o[3] = (bf16_t)gelu_exact(v.w);
    *(bf16x4*)(g + (size_t)idx * 4) = o;
}

// ---------- fused GEMM: C[M,1024] = [gelu(Y) | bases(Y)] @ W^T ----------
__device__ __forceinline__ void gl_lds16(const void* g, void* l) {
    __builtin_amdgcn_global_load_lds(
        (const __attribute__((address_space(1))) unsigned int*)(uintptr_t)g,
        (__attribute__((address_space(3))) unsigned int*)(uintptr_t)l, 16, 0, 0);
}

__device__ __forceinline__ uint64_t pack4bf(float a, float b, float c, float d) {
    union { bf16_t h[4]; uint64_t q; } u;
    u.h[0] = (bf16_t)a; u.h[1] = (bf16_t)b; u.h[2] = (bf16_t)c; u.h[3] = (bf16_t)d;
    return u.q;
}

// Uniform cubic B-spline window: 8 bf16 bases of one feature, as 16 bytes.
// bases[i] = M3(u - i); nonzero window = [j-3, j], weights w0..w3 (w3 at idx j).
__device__ __forceinline__ void spline8(float x, float g0, float invh,
                                        uint64_t& lo, uint64_t& hi) {
    float u = (x - g0) * invh;
    float jf = floorf(u);
    int j = (int)jf;
    float f = u - jf;
    float f2 = f * f, f3 = f2 * f;
    float om = 1.0f - f;
    float w0 = om * om * om * (1.0f / 6.0f);            // M3(3+f)
    float w1 = 0.5f * f3 - f2 + (2.0f / 3.0f);          // M3(2+f)
    float w2 = -0.5f * f3 + 0.5f * f2 + 0.5f * f + (1.0f / 6.0f); // M3(1+f)
    float w3 = f3 * (1.0f / 6.0f);                      // M3(f)
    uint64_t W64 = pack4bf(w0, w1, w2, w3);
    if (!(u >= 0.0f && u < 11.0f)) W64 = 0;             // outside knot span: all bases 0
    int sh = (j - 3) * 16;                              // bit offset of window in 128b
    if (sh >= 0) {
        int s = sh & 63;
        uint64_t shifted = W64 << s;
        uint64_t spill = s ? (W64 >> (64 - s)) : 0ull;
        lo = (sh < 64) ? shifted : 0ull;
        hi = (sh < 64) ? spill : shifted;
    } else {
        lo = W64 >> (-sh);
        hi = 0ull;
    }
}

__global__ __launch_bounds__(256) void gemm_fused(
    const float* __restrict__ Y,       // [R,1024] f32 (raw layer input)
    const bf16_t* __restrict__ G,      // [R,1024] bf16 gelu(Y)
    const bf16_t* __restrict__ W,      // [1024,9216] packed bf16
    float* __restrict__ C,             // [R,1024] f32
    const float* __restrict__ gp,      // this layer's knot row (12 floats, uniform)
    int mmask, int mshift) {
    constexpr int K = KTOT, N = DIM;
    __shared__ __align__(16) bf16_t At[128 * 64];
    __shared__ __align__(16) bf16_t Bt[128 * 64];
    const int tid = threadIdx.x;
    const int l = tid & 63;
    const int w = tid >> 6;
    const int wm = w & 1, wn = w >> 1;
    const int bm = blockIdx.x & mmask, bn = blockIdx.x >> mshift;

    const float g0 = gp[0];
    const float invh = 1.0f / (gp[1] - gp[0]);

    const bf16_t* Gg = G + (size_t)(bm * 128 + (tid >> 3)) * DIM + (tid & 7) * 8;
    const bf16_t* Bg = W + (size_t)(bn * 128 + (tid >> 3)) * K + (tid & 7) * 8;
    bf16_t* Al = At + tid * 8;   // wave-uniform base + lane*16B
    bf16_t* Bl = Bt + tid * 8;
    const float* Yrow = Y + (size_t)(bm * 128 + (tid >> 1)) * DIM + (tid & 1) * 4;
    bf16_t* As = At + (tid >> 1) * 64 + (tid & 1) * 32;  // 4 features * 8 bases

    f32x4 acc[4][4] = {};
    const bf16_t* Ar = At + (wm * 64 + (l & 15)) * 64 + (l >> 4) * 8;
    const bf16_t* Br = Bt + (wn * 64 + (l & 15)) * 64 + (l >> 4) * 8;

    for (int k0 = 0; k0 < K; k0 += 64) {
        if (k0 < DIM) {
            // gelu region: async copy from precomputed gelu(Y)
#pragma unroll
            for (int q = 0; q < 4; q++)
                gl_lds16(Gg + (size_t)q * 32 * DIM + k0, Al + q * 2048);
        } else {
            // spline region: compute 4 features' bases in-register, write LDS
            const int j0 = (k0 - DIM) >> 3;
            float4 xv = *(const float4*)(Yrow + j0);
#pragma unroll
            for (int m = 0; m < 4; m++) {
                float xval = (m == 0) ? xv.x : (m == 1) ? xv.y : (m == 2) ? xv.z : xv.w;
                uint64_t lo, hi;
                spline8(xval, g0, invh, lo, hi);
                union { uint64_t q[2]; uint4 v; } ov;
                ov.q[0] = lo; ov.q[1] = hi;
                *(uint4*)(As + m * 8) = ov.v;
            }
        }
#pragma unroll
        for (int q = 0; q < 4; q++)
            gl_lds16(Bg + (size_t)q * 32 * K + k0, Bl + q * 2048);
        asm volatile("s_waitcnt vmcnt(0)" ::: "memory");
        __syncthreads();
#pragma unroll
        for (int kk = 0; kk < 2; kk++) {
            bf16x8 af[4], bfr[4];
#pragma unroll
            for (int i = 0; i < 4; i++) af[i] = *(const bf16x8*)(Ar + i * 16 * 64 + kk * 32);
#pragma unroll
            for (int j = 0; j < 4; j++) bfr[j] = *(const bf16x8*)(Br + j * 16 * 64 + kk * 32);
#pragma unroll
            for (int i = 0; i < 4; i++)
#pragma unroll
                for (int j = 0; j < 4; j++)
                    acc[i][j] = __builtin_amdgcn_mfma_f32_16x16x32_bf16(af[i], bfr[j], acc[i][j], 0, 0, 0);
        }
        __syncthreads();
    }

    const int r0 = bm * 128 + wm * 64 + (l >> 4) * 4;
    const int c0 = bn * 128 + wn * 64 + (l & 15);
#pragma unroll
    for (int i = 0; i < 4; i++)
#pragma unroll
        for (int j = 0; j < 4; j++)
#pragma unroll
            for (int r = 0; r < 4; r++)
                C[(size_t)(r0 + i * 16 + r) * N + c0 + j * 16] = acc[i][j][r];
}

// ---------- LayerNorm + PReLU -> y (f32) + gelu(y) (bf16) ----------
__global__ void ln_mid(const float* __restrict__ h, const float* __restrict__ g_ln,
                       const float* __restrict__ b_ln, const float* __restrict__ pa,
                       float* __restrict__ y, bf16_t* __restrict__ yg) {
    const int row = blockIdx.x, tid = threadIdx.x;
    const int w = tid >> 6, l = tid & 63;
    f32x4 v = *(const f32x4*)(h + (size_t)row * DIM + tid * 4);
    float s = v[0] + v[1] + v[2] + v[3];
    float q = v[0] * v[0] + v[1] * v[1] + v[2] * v[2] + v[3] * v[3];
#pragma unroll
    for (int o = 32; o > 0; o >>= 1) { s += __shfl_xor(s, o); q += __shfl_xor(q, o); }
    __shared__ float rs[4], rq[4];
    if (l == 0) { rs[w] = s; rq[w] = q; }
    __syncthreads();
    s = rs[0] + rs[1] + rs[2] + rs[3];
    q = rq[0] + rq[1] + rq[2] + rq[3];
    float mean = s * (1.0f / DIM);
    float var = q * (1.0f / DIM) - mean * mean;
    float rstd = rsqrtf(var + LN_EPS);
    float a = pa[0];
    f32x4 o4;
    bf16x4 g4;
#pragma unroll
    for (int c = 0; c < 4; c++) {
        int col = tid * 4 + c;
        float yv = (v[c] - mean) * rstd * g_ln[col] + b_ln[col];
        yv = (yv >= 0.0f) ? yv : a * yv;
        o4[c] = yv;
        g4[c] = (bf16_t)gelu_exact(yv);
    }
    *(f32x4*)(y + (size_t)row * DIM + tid * 4) = o4;
    *(bf16x4*)(yg + (size_t)row * DIM + tid * 4) = g4;
}

// ---------- final LayerNorm + PReLU -> f32 out ----------
__global__ void ln_out(const float* __restrict__ h, const float* __restrict__ g_ln,
                       const float* __restrict__ b_ln, const float* __restrict__ pa,
                       float* __restrict__ out) {
    const int row = blockIdx.x, tid = threadIdx.x;
    const int w = tid >> 6, l = tid & 63;
    f32x4 v = *(const f32x4*)(h + (size_t)row * DIM + tid * 4);
    float s = v[0] + v[1] + v[2] + v[3];
    float q = v[0] * v[0] + v[1] * v[1] + v[2] * v[2] + v[3] * v[3];
#pragma unroll
    for (int o = 32; o > 0; o >>= 1) { s += __shfl_xor(s, o); q += __shfl_xor(q, o); }
    __shared__ float rs[4], rq[4];
    if (l == 0) { rs[w] = s; rq[w] = q; }
    __syncthreads();
    s = rs[0] + rs[1] + rs[2] + rs[3];
    q = rq[0] + rq[1] + rq[2] + rq[3];
    float mean = s * (1.0f / DIM);
    float var = q * (1.0f / DIM) - mean * mean;
    float rstd = rsqrtf(var + LN_EPS);
    float a = pa[0];
    f32x4 o4;
#pragma unroll
    for (int c = 0; c < 4; c++) {
        int col = tid * 4 + c;
        float yv = (v[c] - mean) * rstd * g_ln[col] + b_ln[col];
        o4[c] = (yv >= 0.0f) ? yv : a * yv;
    }
    *(f32x4*)(out + (size_t)row * DIM + tid * 4) = o4;
}

// ---------- launch ----------
extern "C" void kernel_launch(void* const* d_in, const int* in_sizes, int n_in,
                              void* d_out, int out_size, void* d_ws, size_t ws_size,
                              hipStream_t stream) {
    const float* x    = (const float*)d_in[0];
    const float* bw   = (const float*)d_in[1];
    const float* sw   = (const float*)d_in[2];
    const float* ln_g = (const float*)d_in[3];
    const float* ln_b = (const float*)d_in[4];
    const float* pa   = (const float*)d_in[5];
    const float* grid = (const float*)d_in[6];
    float* out = (float*)d_out;

    const size_t wbytes = (size_t)2 * DIM * KTOT * sizeof(bf16_t);   // 37.75 MB
    // slab R rows: needs ygelu (2B) + y (4B) + h (4B) per element
    int R = 8192;
    while (R > 128 && wbytes + (size_t)R * DIM * 10 > ws_size) R >>= 1;
    int mtiles = R / 128;
    int mshift = 0; while ((1 << mshift) < mtiles) mshift++;
    int mmask = mtiles - 1;

    char* wsc = (char*)d_ws;
    bf16_t* Wbuf = (bf16_t*)wsc;
    bf16_t* ygel = (bf16_t*)(wsc + wbytes);
    float*  ybuf = (float*)(wsc + wbytes + (size_t)R * DIM * 2);
    float*  hbuf = (float*)(wsc + wbytes + (size_t)R * DIM * 6);

    pack_w<<<(2 * DIM * DIM) / 256, 256, 0, stream>>>(bw, sw, Wbuf);

    const int nslab = BATCH / R;
    for (int sidx = 0; sidx < nslab; sidx++) {
        const size_t row0 = (size_t)sidx * R;
        const float* x0 = x + row0 * DIM;
        // layer 0
        prep_gelu<<<R * DIM / 1024, 256, 0, stream>>>(x0, ygel);
        gemm_fused<<<mtiles * 8, 256, 0, stream>>>(x0, ygel, Wbuf, hbuf,
                                                   grid, mmask, mshift);
        ln_mid<<<R, 256, 0, stream>>>(hbuf, ln_g, ln_b, pa, ybuf, ygel);
        // layer 1
        gemm_fused<<<mtiles * 8, 256, 0, stream>>>(ybuf, ygel, Wbuf + (size_t)DIM * KTOT, hbuf,
                                                   grid + DIM * NKNOT, mmask, mshift);
        ln_out<<<R, 256, 0, stream>>>(hbuf, ln_g + DIM, ln_b + DIM, pa + 1, out + row0 * DIM);
    }
}

// Round 3
// 646.304 us; speedup vs baseline: 1.5352x; 1.1675x over previous
//
#include <hip/hip_runtime.h>
#include <hip/hip_bf16.h>
#include <cstdint>
#include <cstddef>

// ---------- types ----------
typedef __bf16 bf16_t;
typedef __bf16 bf16x8 __attribute__((ext_vector_type(8)));
typedef __bf16 bf16x4 __attribute__((ext_vector_type(4)));
typedef float  f32x4  __attribute__((ext_vector_type(4)));

#define DIM    1024
#define NCOEF  8
#define KTOT   (DIM + DIM * NCOEF)   // 9216
#define NKNOT  12
#define BATCH  8192
#define LN_EPS 1e-5f

// ---------- device helpers ----------
__device__ __forceinline__ float gelu_exact(float x) {
    return 0.5f * x * (1.0f + erff(x * 0.70710678118654752440f));
}

// ---------- W pack: [base_w | spline_w] f32 -> bf16, K-packed ----------
__global__ void pack_w(const float* __restrict__ bw, const float* __restrict__ sw,
                       bf16_t* __restrict__ W) {
    int idx = blockIdx.x * 256 + threadIdx.x;      // (layer,o,j)
    bf16_t* wrow = W + (size_t)(idx >> 10) * KTOT;
    int j = idx & 1023;
    wrow[j] = (bf16_t)bw[idx];
    const float4* sp = (const float4*)(sw + (size_t)idx * NCOEF);
    float4 s0 = sp[0], s1 = sp[1];
    bf16x8 v;
    v[0] = (bf16_t)s0.x; v[1] = (bf16_t)s0.y; v[2] = (bf16_t)s0.z; v[3] = (bf16_t)s0.w;
    v[4] = (bf16_t)s1.x; v[5] = (bf16_t)s1.y; v[6] = (bf16_t)s1.z; v[7] = (bf16_t)s1.w;
    *(bf16x8*)(wrow + DIM + j * NCOEF) = v;
}

// ---------- gelu precompute: f32 x -> bf16 gelu(x) ----------
__global__ void prep_gelu(const float* __restrict__ x, bf16_t* __restrict__ g) {
    int idx = blockIdx.x * 256 + threadIdx.x;
    float4 v = ((const float4*)x)[idx];
    bf16x4 o;
    o[0] = (bf16_t)gelu_exact(v.x); o[1] = (bf16_t)gelu_exact(v.y);
    o[2] = (bf16_t)gelu_exact(v.z); o[3] = (bf16_t)gelu_exact(v.w);
    *(bf16x4*)(g + (size_t)idx * 4) = o;
}

// ---------- fused GEMM ----------
__device__ __forceinline__ void gl_lds16(const void* g, void* l) {
    __builtin_amdgcn_global_load_lds(
        (const __attribute__((address_space(1))) unsigned int*)(uintptr_t)g,
        (__attribute__((address_space(3))) unsigned int*)(uintptr_t)l, 16, 0, 0);
}

__device__ __forceinline__ uint64_t pack4bf(float a, float b, float c, float d) {
    union { bf16_t h[4]; uint64_t q; } u;
    u.h[0] = (bf16_t)a; u.h[1] = (bf16_t)b; u.h[2] = (bf16_t)c; u.h[3] = (bf16_t)d;
    return u.q;
}

// Uniform cubic B-spline: 8 bf16 bases of one feature as 16 bytes (lo,hi).
__device__ __forceinline__ void spline8(float x, float g0, float invh,
                                        uint64_t& lo, uint64_t& hi) {
    float u = (x - g0) * invh;
    float jf = floorf(u);
    int j = (int)jf;
    float f = u - jf;
    float f2 = f * f, f3 = f2 * f;
    float om = 1.0f - f, om2 = om * om;
    float w0 = om2 * om * (1.0f / 6.0f);
    float w3 = f3 * (1.0f / 6.0f);
    float w1 = fmaf(0.5f, f3, 2.0f / 3.0f) - f2;
    float w2 = 1.0f - w0 - w1 - w3;       // partition of unity (exact identity)
    uint64_t W64 = pack4bf(w0, w1, w2, w3);
    if (!(u >= 0.0f && u < 11.0f)) W64 = 0;
    int sh = (j - 3) * 16;                // bit pos of w0 in the 128-bit window
    if (sh >= 0) {
        int s = sh & 63;
        uint64_t loW = W64 << s;
        uint64_t hiW = s ? (W64 >> (64 - s)) : 0ull;
        lo = (sh < 64) ? loW : 0ull;
        hi = (sh < 64) ? hiW : loW;
    } else {
        lo = W64 >> (-sh);
        hi = 0ull;
    }
}

__device__ __forceinline__ void mfma_tile(const bf16_t* __restrict__ Ar,
                                          const bf16_t* __restrict__ Br,
                                          f32x4 (&acc)[4][4]) {
#pragma unroll
    for (int kk = 0; kk < 2; kk++) {
        bf16x8 af[4], bfr[4];
#pragma unroll
        for (int i = 0; i < 4; i++) af[i] = *(const bf16x8*)(Ar + i * 16 * 64 + kk * 32);
#pragma unroll
        for (int j = 0; j < 4; j++) bfr[j] = *(const bf16x8*)(Br + j * 16 * 64 + kk * 32);
#pragma unroll
        for (int i = 0; i < 4; i++)
#pragma unroll
            for (int j = 0; j < 4; j++)
                acc[i][j] = __builtin_amdgcn_mfma_f32_16x16x32_bf16(af[i], bfr[j], acc[i][j], 0, 0, 0);
    }
}

__global__ __launch_bounds__(256) void gemm_fused(
    const float* __restrict__ Y,       // [R,1024] f32 (raw layer input)
    const bf16_t* __restrict__ G,      // [R,1024] bf16 gelu(Y)
    const bf16_t* __restrict__ W,      // [1024,9216] packed bf16
    float* __restrict__ C,             // [R,1024] f32
    const float* __restrict__ gp,      // knot row (12 floats, uniform)
    int mmask, int mshift) {
    constexpr int K = KTOT, N = DIM;
    __shared__ __align__(16) bf16_t At[128 * 64];
    __shared__ __align__(16) bf16_t Bt[128 * 64];
    const int tid = threadIdx.x;
    const int l = tid & 63;
    const int w = tid >> 6;
    const int wm = w & 1, wn = w >> 1;
    const int bm = blockIdx.x & mmask, bn = blockIdx.x >> mshift;

    const float g0 = gp[0];
    const float invh = 1.0f / (gp[1] - gp[0]);

    const bf16_t* Gg = G + (size_t)(bm * 128 + (tid >> 3)) * DIM + (tid & 7) * 8;
    const bf16_t* Bg = W + (size_t)(bn * 128 + (tid >> 3)) * K + (tid & 7) * 8;
    bf16_t* Al = At + tid * 8;          // wave-uniform base + lane*16B
    bf16_t* Bl = Bt + tid * 8;

    // spline-region mapping: thread owns (row = (tid>>3)+32q, feature = j0+(tid&7))
    // LDS write addr row*128B + (tid&7)*16B -> lanes 0..7 span all 32 banks.
    const float* Yb = Y + (size_t)(bm * 128 + (tid >> 3)) * DIM + (tid & 7);
    bf16_t* As = At + (tid >> 3) * 64 + (tid & 7) * 8;

    f32x4 acc[4][4] = {};
    const bf16_t* Ar = At + (wm * 64 + (l & 15)) * 64 + (l >> 4) * 8;
    const bf16_t* Br = Bt + (wn * 64 + (l & 15)) * 64 + (l >> 4) * 8;

    // ---- gelu region: K = [0, 1024) ----
    for (int k0 = 0; k0 < DIM; k0 += 64) {
#pragma unroll
        for (int q = 0; q < 4; q++) {
            gl_lds16(Gg + (size_t)q * 32 * DIM + k0, Al + q * 2048);
            gl_lds16(Bg + (size_t)q * 32 * K + k0, Bl + q * 2048);
        }
        asm volatile("s_waitcnt vmcnt(0)" ::: "memory");
        __syncthreads();
        mfma_tile(Ar, Br, acc);
        __syncthreads();
    }

    // ---- spline region: K = [1024, 9216) ----
    float ycur[4], ynext[4];
#pragma unroll
    for (int q = 0; q < 4; q++) ycur[q] = Yb[(size_t)q * 32 * DIM];

    for (int k0 = DIM; k0 < K; k0 += 64) {
        const int j0 = (k0 - DIM) >> 3;
        const bool more = (k0 + 64) < K;
        if (more) {
#pragma unroll
            for (int q = 0; q < 4; q++) ynext[q] = Yb[(size_t)q * 32 * DIM + j0 + 8];
        }
#pragma unroll
        for (int q = 0; q < 4; q++)
            gl_lds16(Bg + (size_t)q * 32 * K + k0, Bl + q * 2048);
        // compute this iter's bases from prefetched ycur (no global dependency)
#pragma unroll
        for (int q = 0; q < 4; q++) {
            uint64_t lo, hi;
            spline8(ycur[q], g0, invh, lo, hi);
            union { uint64_t u[2]; uint4 v; } ov;
            ov.u[0] = lo; ov.u[1] = hi;
            *(uint4*)(As + q * 32 * 64) = ov.v;
        }
        asm volatile("s_waitcnt vmcnt(0)" ::: "memory");
        __syncthreads();
        mfma_tile(Ar, Br, acc);
        __syncthreads();
        if (more) {
#pragma unroll
            for (int q = 0; q < 4; q++) ycur[q] = ynext[q];
        }
    }

    const int r0 = bm * 128 + wm * 64 + (l >> 4) * 4;
    const int c0 = bn * 128 + wn * 64 + (l & 15);
#pragma unroll
    for (int i = 0; i < 4; i++)
#pragma unroll
        for (int j = 0; j < 4; j++)
#pragma unroll
            for (int r = 0; r < 4; r++)
                C[(size_t)(r0 + i * 16 + r) * N + c0 + j * 16] = acc[i][j][r];
}

// ---------- LayerNorm + PReLU -> y (f32) + gelu(y) (bf16) ----------
__global__ void ln_mid(const float* __restrict__ h, const float* __restrict__ g_ln,
                       const float* __restrict__ b_ln, const float* __restrict__ pa,
                       float* __restrict__ y, bf16_t* __restrict__ yg) {
    const int row = blockIdx.x, tid = threadIdx.x;
    const int w = tid >> 6, l = tid & 63;
    f32x4 v = *(const f32x4*)(h + (size_t)row * DIM + tid * 4);
    float s = v[0] + v[1] + v[2] + v[3];
    float q = v[0] * v[0] + v[1] * v[1] + v[2] * v[2] + v[3] * v[3];
#pragma unroll
    for (int o = 32; o > 0; o >>= 1) { s += __shfl_xor(s, o); q += __shfl_xor(q, o); }
    __shared__ float rs[4], rq[4];
    if (l == 0) { rs[w] = s; rq[w] = q; }
    __syncthreads();
    s = rs[0] + rs[1] + rs[2] + rs[3];
    q = rq[0] + rq[1] + rq[2] + rq[3];
    float mean = s * (1.0f / DIM);
    float var = q * (1.0f / DIM) - mean * mean;
    float rstd = rsqrtf(var + LN_EPS);
    float a = pa[0];
    f32x4 o4;
    bf16x4 g4;
#pragma unroll
    for (int c = 0; c < 4; c++) {
        int col = tid * 4 + c;
        float yv = (v[c] - mean) * rstd * g_ln[col] + b_ln[col];
        yv = (yv >= 0.0f) ? yv : a * yv;
        o4[c] = yv;
        g4[c] = (bf16_t)gelu_exact(yv);
    }
    *(f32x4*)(y + (size_t)row * DIM + tid * 4) = o4;
    *(bf16x4*)(yg + (size_t)row * DIM + tid * 4) = g4;
}

// ---------- final LayerNorm + PReLU -> f32 out ----------
__global__ void ln_out(const float* __restrict__ h, const float* __restrict__ g_ln,
                       const float* __restrict__ b_ln, const float* __restrict__ pa,
                       float* __restrict__ out) {
    const int row = blockIdx.x, tid = threadIdx.x;
    const int w = tid >> 6, l = tid & 63;
    f32x4 v = *(const f32x4*)(h + (size_t)row * DIM + tid * 4);
    float s = v[0] + v[1] + v[2] + v[3];
    float q = v[0] * v[0] + v[1] * v[1] + v[2] * v[2] + v[3] * v[3];
#pragma unroll
    for (int o = 32; o > 0; o >>= 1) { s += __shfl_xor(s, o); q += __shfl_xor(q, o); }
    __shared__ float rs[4], rq[4];
    if (l == 0) { rs[w] = s; rq[w] = q; }
    __syncthreads();
    s = rs[0] + rs[1] + rs[2] + rs[3];
    q = rq[0] + rq[1] + rq[2] + rq[3];
    float mean = s * (1.0f / DIM);
    float var = q * (1.0f / DIM) - mean * mean;
    float rstd = rsqrtf(var + LN_EPS);
    float a = pa[0];
    f32x4 o4;
#pragma unroll
    for (int c = 0; c < 4; c++) {
        int col = tid * 4 + c;
        float yv = (v[c] - mean) * rstd * g_ln[col] + b_ln[col];
        o4[c] = (yv >= 0.0f) ? yv : a * yv;
    }
    *(f32x4*)(out + (size_t)row * DIM + tid * 4) = o4;
}

// ---------- launch ----------
extern "C" void kernel_launch(void* const* d_in, const int* in_sizes, int n_in,
                              void* d_out, int out_size, void* d_ws, size_t ws_size,
                              hipStream_t stream) {
    const float* x    = (const float*)d_in[0];
    const float* bw   = (const float*)d_in[1];
    const float* sw   = (const float*)d_in[2];
    const float* ln_g = (const float*)d_in[3];
    const float* ln_b = (const float*)d_in[4];
    const float* pa   = (const float*)d_in[5];
    const float* grid = (const float*)d_in[6];
    float* out = (float*)d_out;

    const size_t wbytes = (size_t)2 * DIM * KTOT * sizeof(bf16_t);   // 37.75 MB
    int R = 8192;
    while (R > 128 && wbytes + (size_t)R * DIM * 10 > ws_size) R >>= 1;
    int mtiles = R / 128;
    int mshift = 0; while ((1 << mshift) < mtiles) mshift++;
    int mmask = mtiles - 1;

    char* wsc = (char*)d_ws;
    bf16_t* Wbuf = (bf16_t*)wsc;
    bf16_t* ygel = (bf16_t*)(wsc + wbytes);
    float*  ybuf = (float*)(wsc + wbytes + (size_t)R * DIM * 2);
    float*  hbuf = (float*)(wsc + wbytes + (size_t)R * DIM * 6);

    pack_w<<<(2 * DIM * DIM) / 256, 256, 0, stream>>>(bw, sw, Wbuf);

    const int nslab = BATCH / R;
    for (int sidx = 0; sidx < nslab; sidx++) {
        const size_t row0 = (size_t)sidx * R;
        const float* x0 = x + row0 * DIM;
        // layer 0
        prep_gelu<<<R * DIM / 1024, 256, 0, stream>>>(x0, ygel);
        gemm_fused<<<mtiles * 8, 256, 0, stream>>>(x0, ygel, Wbuf, hbuf,
                                                   grid, mmask, mshift);
        ln_mid<<<R, 256, 0, stream>>>(hbuf, ln_g, ln_b, pa, ybuf, ygel);
        // layer 1
        gemm_fused<<<mtiles * 8, 256, 0, stream>>>(ybuf, ygel, Wbuf + (size_t)DIM * KTOT, hbuf,
                                                   grid + DIM * NKNOT, mmask, mshift);
        ln_out<<<R, 256, 0, stream>>>(hbuf, ln_g + DIM, ln_b + DIM, pa + 1, out + row0 * DIM);
    }
}

// Round 4
// 569.815 us; speedup vs baseline: 1.7413x; 1.1342x over previous
//
#include <hip/hip_runtime.h>
#include <hip/hip_bf16.h>
#include <cstdint>
#include <cstddef>

// ---------- types ----------
typedef __bf16 bf16_t;
typedef __bf16 bf16x8 __attribute__((ext_vector_type(8)));
typedef __bf16 bf16x4 __attribute__((ext_vector_type(4)));
typedef float  f32x4  __attribute__((ext_vector_type(4)));

#define DIM    1024
#define NCOEF  8
#define KTOT   (DIM + DIM * NCOEF)   // 9216
#define NKNOT  12
#define BATCH  8192
#define LN_EPS 1e-5f

// ---------- device helpers ----------
__device__ __forceinline__ float gelu_exact(float x) {
    return 0.5f * x * (1.0f + erff(x * 0.70710678118654752440f));
}

// ---------- W pack: [base_w | spline_w] f32 -> bf16, K-packed ----------
__global__ void pack_w(const float* __restrict__ bw, const float* __restrict__ sw,
                       bf16_t* __restrict__ W) {
    int idx = blockIdx.x * 256 + threadIdx.x;      // (layer,o,j)
    bf16_t* wrow = W + (size_t)(idx >> 10) * KTOT;
    int j = idx & 1023;
    wrow[j] = (bf16_t)bw[idx];
    const float4* sp = (const float4*)(sw + (size_t)idx * NCOEF);
    float4 s0 = sp[0], s1 = sp[1];
    bf16x8 v;
    v[0] = (bf16_t)s0.x; v[1] = (bf16_t)s0.y; v[2] = (bf16_t)s0.z; v[3] = (bf16_t)s0.w;
    v[4] = (bf16_t)s1.x; v[5] = (bf16_t)s1.y; v[6] = (bf16_t)s1.z; v[7] = (bf16_t)s1.w;
    *(bf16x8*)(wrow + DIM + j * NCOEF) = v;
}

// ---------- gelu precompute: f32 x -> bf16 gelu(x) ----------
__global__ void prep_gelu(const float* __restrict__ x, bf16_t* __restrict__ g) {
    int idx = blockIdx.x * 256 + threadIdx.x;
    float4 v = ((const float4*)x)[idx];
    bf16x4 o;
    o[0] = (bf16_t)gelu_exact(v.x); o[1] = (bf16_t)gelu_exact(v.y);
    o[2] = (bf16_t)gelu_exact(v.z); o[3] = (bf16_t)gelu_exact(v.w);
    *(bf16x4*)(g + (size_t)idx * 4) = o;
}

// ---------- fused GEMM ----------
__device__ __forceinline__ void gl_lds16(const void* g, void* l) {
    __builtin_amdgcn_global_load_lds(
        (const __attribute__((address_space(1))) unsigned int*)(uintptr_t)g,
        (__attribute__((address_space(3))) unsigned int*)(uintptr_t)l, 16, 0, 0);
}

__device__ __forceinline__ uint64_t pack4bf(float a, float b, float c, float d) {
    union { bf16_t h[4]; uint64_t q; } u;
    u.h[0] = (bf16_t)a; u.h[1] = (bf16_t)b; u.h[2] = (bf16_t)c; u.h[3] = (bf16_t)d;
    return u.q;
}

// Uniform cubic B-spline: 8 bf16 bases of one feature as 16 bytes (lo,hi).
__device__ __forceinline__ void spline8(float x, float g0, float invh,
                                        uint64_t& lo, uint64_t& hi) {
    float u = (x - g0) * invh;
    float jf = floorf(u);
    int j = (int)jf;
    float f = u - jf;
    float f2 = f * f, f3 = f2 * f;
    float om = 1.0f - f, om2 = om * om;
    float w0 = om2 * om * (1.0f / 6.0f);
    float w3 = f3 * (1.0f / 6.0f);
    float w1 = fmaf(0.5f, f3, 2.0f / 3.0f) - f2;
    float w2 = 1.0f - w0 - w1 - w3;       // partition of unity (exact identity)
    uint64_t W64 = pack4bf(w0, w1, w2, w3);
    if (!(u >= 0.0f && u < 11.0f)) W64 = 0;
    int sh = (j - 3) * 16;                // bit pos of w0 in the 128-bit window
    if (sh >= 0) {
        int s = sh & 63;
        uint64_t loW = W64 << s;
        uint64_t hiW = s ? (W64 >> (64 - s)) : 0ull;
        lo = (sh < 64) ? loW : 0ull;
        hi = (sh < 64) ? hiW : loW;
    } else {
        lo = W64 >> (-sh);
        hi = 0ull;
    }
}

// LDS layout: row stride 64 elem (128 B); physical 16B-chunk = logical ^ (row&7).
// Fragment reads pass swizzle-resolved pointers (kk=0 uses c0, kk=1 uses c0^4).
__device__ __forceinline__ void mfma_tile(const bf16_t* __restrict__ Ar0,
                                          const bf16_t* __restrict__ Ar1,
                                          const bf16_t* __restrict__ Br0,
                                          const bf16_t* __restrict__ Br1,
                                          f32x4 (&acc)[4][4]) {
#pragma unroll
    for (int kk = 0; kk < 2; kk++) {
        const bf16_t* Ar = kk ? Ar1 : Ar0;
        const bf16_t* Br = kk ? Br1 : Br0;
        bf16x8 af[4], bfr[4];
#pragma unroll
        for (int i = 0; i < 4; i++) af[i] = *(const bf16x8*)(Ar + i * 16 * 64);
#pragma unroll
        for (int j = 0; j < 4; j++) bfr[j] = *(const bf16x8*)(Br + j * 16 * 64);
#pragma unroll
        for (int i = 0; i < 4; i++)
#pragma unroll
            for (int j = 0; j < 4; j++)
                acc[i][j] = __builtin_amdgcn_mfma_f32_16x16x32_bf16(af[i], bfr[j], acc[i][j], 0, 0, 0);
    }
}

__global__ __launch_bounds__(256) void gemm_fused(
    const float* __restrict__ Y,       // [R,1024] f32 (raw layer input)
    const bf16_t* __restrict__ G,      // [R,1024] bf16 gelu(Y)
    const bf16_t* __restrict__ W,      // [1024,9216] packed bf16
    float* __restrict__ C,             // [R,1024] f32
    const float* __restrict__ gp,      // knot row (12 floats, uniform)
    int mmask, int mshift) {
    constexpr int K = KTOT, N = DIM;
    __shared__ __align__(16) bf16_t At[128 * 64];
    __shared__ __align__(16) bf16_t Bt[128 * 64];
    const int tid = threadIdx.x;
    const int l = tid & 63;
    const int w = tid >> 6;
    const int wm = w & 1, wn = w >> 1;
    const int bm = blockIdx.x & mmask, bn = blockIdx.x >> mshift;

    const float g0 = gp[0];
    const float invh = 1.0f / (gp[1] - gp[0]);

    // DMA slot for thread tid = LDS bytes [tid*16, tid*16+16) = row tid>>3, chunk tid&7.
    // That slot must hold LOGICAL chunk (tid&7)^(row&7) of its row.
    const int lrow = tid >> 3;
    const int lchk = (tid & 7) ^ (lrow & 7);
    const bf16_t* Gg = G + (size_t)(bm * 128 + lrow) * DIM + lchk * 8;
    const bf16_t* Bg = W + (size_t)(bn * 128 + lrow) * K + lchk * 8;
    bf16_t* Al = At + tid * 8;          // wave-uniform base + lane*16B
    bf16_t* Bl = Bt + tid * 8;

    // spline region: thread owns (rows lrow+32q, feature j0+(tid&7));
    // logical chunk tid&7 -> physical chunk (tid&7)^(lrow&7) == lchk.
    const float* Yb = Y + (size_t)(bm * 128 + lrow) * DIM + (tid & 7);
    bf16_t* As = At + lrow * 64 + lchk * 8;

    f32x4 acc[4][4] = {};
    // fragment reads: row r = base+(l&15) (+16i), r&7 = l&7; chunk(kk) = ((l>>4)+4kk)^(l&7)
    const int cA = (l >> 4) ^ (l & 7);
    const bf16_t* Ar0 = At + (wm * 64 + (l & 15)) * 64 + cA * 8;
    const bf16_t* Ar1 = At + (wm * 64 + (l & 15)) * 64 + (cA ^ 4) * 8;
    const bf16_t* Br0 = Bt + (wn * 64 + (l & 15)) * 64 + cA * 8;
    const bf16_t* Br1 = Bt + (wn * 64 + (l & 15)) * 64 + (cA ^ 4) * 8;

    // ---- gelu region: K = [0, 1024) ----
    for (int k0 = 0; k0 < DIM; k0 += 64) {
#pragma unroll
        for (int q = 0; q < 4; q++) {
            gl_lds16(Gg + (size_t)q * 32 * DIM + k0, Al + q * 2048);
            gl_lds16(Bg + (size_t)q * 32 * K + k0, Bl + q * 2048);
        }
        asm volatile("s_waitcnt vmcnt(0)" ::: "memory");
        __syncthreads();
        mfma_tile(Ar0, Ar1, Br0, Br1, acc);
        __syncthreads();
    }

    // ---- spline region: K = [1024, 9216) ----
    float ycur[4], ynext[4];
#pragma unroll
    for (int q = 0; q < 4; q++) ycur[q] = Yb[(size_t)q * 32 * DIM];

    for (int k0 = DIM; k0 < K; k0 += 64) {
        const int j0 = (k0 - DIM) >> 3;
        const bool more = (k0 + 64) < K;
        if (more) {
#pragma unroll
            for (int q = 0; q < 4; q++) ynext[q] = Yb[(size_t)q * 32 * DIM + j0 + 8];
        }
#pragma unroll
        for (int q = 0; q < 4; q++)
            gl_lds16(Bg + (size_t)q * 32 * K + k0, Bl + q * 2048);
        // compute this iter's bases from prefetched ycur (no global dependency)
#pragma unroll
        for (int q = 0; q < 4; q++) {
            uint64_t lo, hi;
            spline8(ycur[q], g0, invh, lo, hi);
            union { uint64_t u[2]; uint4 v; } ov;
            ov.u[0] = lo; ov.u[1] = hi;
            *(uint4*)(As + q * 32 * 64) = ov.v;
        }
        asm volatile("s_waitcnt vmcnt(0)" ::: "memory");
        __syncthreads();
        mfma_tile(Ar0, Ar1, Br0, Br1, acc);
        __syncthreads();
        if (more) {
#pragma unroll
            for (int q = 0; q < 4; q++) ycur[q] = ynext[q];
        }
    }

    const int r0 = bm * 128 + wm * 64 + (l >> 4) * 4;
    const int c0 = bn * 128 + wn * 64 + (l & 15);
#pragma unroll
    for (int i = 0; i < 4; i++)
#pragma unroll
        for (int j = 0; j < 4; j++)
#pragma unroll
            for (int r = 0; r < 4; r++)
                C[(size_t)(r0 + i * 16 + r) * N + c0 + j * 16] = acc[i][j][r];
}

// ---------- LayerNorm + PReLU -> y (f32) + gelu(y) (bf16) ----------
__global__ void ln_mid(const float* __restrict__ h, const float* __restrict__ g_ln,
                       const float* __restrict__ b_ln, const float* __restrict__ pa,
                       float* __restrict__ y, bf16_t* __restrict__ yg) {
    const int row = blockIdx.x, tid = threadIdx.x;
    const int w = tid >> 6, l = tid & 63;
    f32x4 v = *(const f32x4*)(h + (size_t)row * DIM + tid * 4);
    float s = v[0] + v[1] + v[2] + v[3];
    float q = v[0] * v[0] + v[1] * v[1] + v[2] * v[2] + v[3] * v[3];
#pragma unroll
    for (int o = 32; o > 0; o >>= 1) { s += __shfl_xor(s, o); q += __shfl_xor(q, o); }
    __shared__ float rs[4], rq[4];
    if (l == 0) { rs[w] = s; rq[w] = q; }
    __syncthreads();
    s = rs[0] + rs[1] + rs[2] + rs[3];
    q = rq[0] + rq[1] + rq[2] + rq[3];
    float mean = s * (1.0f / DIM);
    float var = q * (1.0f / DIM) - mean * mean;
    float rstd = rsqrtf(var + LN_EPS);
    float a = pa[0];
    f32x4 o4;
    bf16x4 g4;
#pragma unroll
    for (int c = 0; c < 4; c++) {
        int col = tid * 4 + c;
        float yv = (v[c] - mean) * rstd * g_ln[col] + b_ln[col];
        yv = (yv >= 0.0f) ? yv : a * yv;
        o4[c] = yv;
        g4[c] = (bf16_t)gelu_exact(yv);
    }
    *(f32x4*)(y + (size_t)row * DIM + tid * 4) = o4;
    *(bf16x4*)(yg + (size_t)row * DIM + tid * 4) = g4;
}

// ---------- final LayerNorm + PReLU -> f32 out ----------
__global__ void ln_out(const float* __restrict__ h, const float* __restrict__ g_ln,
                       const float* __restrict__ b_ln, const float* __restrict__ pa,
                       float* __restrict__ out) {
    const int row = blockIdx.x, tid = threadIdx.x;
    const int w = tid >> 6, l = tid & 63;
    f32x4 v = *(const f32x4*)(h + (size_t)row * DIM + tid * 4);
    float s = v[0] + v[1] + v[2] + v[3];
    float q = v[0] * v[0] + v[1] * v[1] + v[2] * v[2] + v[3] * v[3];
#pragma unroll
    for (int o = 32; o > 0; o >>= 1) { s += __shfl_xor(s, o); q += __shfl_xor(q, o); }
    __shared__ float rs[4], rq[4];
    if (l == 0) { rs[w] = s; rq[w] = q; }
    __syncthreads();
    s = rs[0] + rs[1] + rs[2] + rs[3];
    q = rq[0] + rq[1] + rq[2] + rq[3];
    float mean = s * (1.0f / DIM);
    float var = q * (1.0f / DIM) - mean * mean;
    float rstd = rsqrtf(var + LN_EPS);
    float a = pa[0];
    f32x4 o4;
#pragma unroll
    for (int c = 0; c < 4; c++) {
        int col = tid * 4 + c;
        float yv = (v[c] - mean) * rstd * g_ln[col] + b_ln[col];
        o4[c] = (yv >= 0.0f) ? yv : a * yv;
    }
    *(f32x4*)(out + (size_t)row * DIM + tid * 4) = o4;
}

// ---------- launch ----------
extern "C" void kernel_launch(void* const* d_in, const int* in_sizes, int n_in,
                              void* d_out, int out_size, void* d_ws, size_t ws_size,
                              hipStream_t stream) {
    const float* x    = (const float*)d_in[0];
    const float* bw   = (const float*)d_in[1];
    const float* sw   = (const float*)d_in[2];
    const float* ln_g = (const float*)d_in[3];
    const float* ln_b = (const float*)d_in[4];
    const float* pa   = (const float*)d_in[5];
    const float* grid = (const float*)d_in[6];
    float* out = (float*)d_out;

    const size_t wbytes = (size_t)2 * DIM * KTOT * sizeof(bf16_t);   // 37.75 MB
    int R = 8192;
    while (R > 128 && wbytes + (size_t)R * DIM * 10 > ws_size) R >>= 1;
    int mtiles = R / 128;
    int mshift = 0; while ((1 << mshift) < mtiles) mshift++;
    int mmask = mtiles - 1;

    char* wsc = (char*)d_ws;
    bf16_t* Wbuf = (bf16_t*)wsc;
    bf16_t* ygel = (bf16_t*)(wsc + wbytes);
    float*  ybuf = (float*)(wsc + wbytes + (size_t)R * DIM * 2);
    float*  hbuf = (float*)(wsc + wbytes + (size_t)R * DIM * 6);

    pack_w<<<(2 * DIM * DIM) / 256, 256, 0, stream>>>(bw, sw, Wbuf);

    const int nslab = BATCH / R;
    for (int sidx = 0; sidx < nslab; sidx++) {
        const size_t row0 = (size_t)sidx * R;
        const float* x0 = x + row0 * DIM;
        // layer 0
        prep_gelu<<<R * DIM / 1024, 256, 0, stream>>>(x0, ygel);
        gemm_fused<<<mtiles * 8, 256, 0, stream>>>(x0, ygel, Wbuf, hbuf,
                                                   grid, mmask, mshift);
        ln_mid<<<R, 256, 0, stream>>>(hbuf, ln_g, ln_b, pa, ybuf, ygel);
        // layer 1
        gemm_fused<<<mtiles * 8, 256, 0, stream>>>(ybuf, ygel, Wbuf + (size_t)DIM * KTOT, hbuf,
                                                   grid + DIM * NKNOT, mmask, mshift);
        ln_out<<<R, 256, 0, stream>>>(hbuf, ln_g + DIM, ln_b + DIM, pa + 1, out + row0 * DIM);
    }
}

// Round 5
// 524.251 us; speedup vs baseline: 1.8926x; 1.0869x over previous
//
#include <hip/hip_runtime.h>
#include <hip/hip_bf16.h>
#include <cstdint>
#include <cstddef>

// ---------- types ----------
typedef __bf16 bf16_t;
typedef __bf16 bf16x8 __attribute__((ext_vector_type(8)));
typedef __bf16 bf16x4 __attribute__((ext_vector_type(4)));
typedef float  f32x4  __attribute__((ext_vector_type(4)));

#define DIM    1024
#define NCOEF  8
#define KTOT   (DIM + DIM * NCOEF)   // 9216
#define NKNOT  12
#define BATCH  8192
#define LN_EPS 1e-5f

// ---------- device helpers ----------
__device__ __forceinline__ float gelu_exact(float x) {
    return 0.5f * x * (1.0f + erff(x * 0.70710678118654752440f));
}

// ---------- W pack: [base_w | spline_w] f32 -> bf16, K-packed ----------
__global__ void pack_w(const float* __restrict__ bw, const float* __restrict__ sw,
                       bf16_t* __restrict__ W) {
    int idx = blockIdx.x * 256 + threadIdx.x;      // (layer,o,j)
    bf16_t* wrow = W + (size_t)(idx >> 10) * KTOT;
    int j = idx & 1023;
    wrow[j] = (bf16_t)bw[idx];
    const float4* sp = (const float4*)(sw + (size_t)idx * NCOEF);
    float4 s0 = sp[0], s1 = sp[1];
    bf16x8 v;
    v[0] = (bf16_t)s0.x; v[1] = (bf16_t)s0.y; v[2] = (bf16_t)s0.z; v[3] = (bf16_t)s0.w;
    v[4] = (bf16_t)s1.x; v[5] = (bf16_t)s1.y; v[6] = (bf16_t)s1.z; v[7] = (bf16_t)s1.w;
    *(bf16x8*)(wrow + DIM + j * NCOEF) = v;
}

// ---------- gelu precompute: f32 x -> bf16 gelu(x) ----------
__global__ void prep_gelu(const float* __restrict__ x, bf16_t* __restrict__ g) {
    int idx = blockIdx.x * 256 + threadIdx.x;
    float4 v = ((const float4*)x)[idx];
    bf16x4 o;
    o[0] = (bf16_t)gelu_exact(v.x); o[1] = (bf16_t)gelu_exact(v.y);
    o[2] = (bf16_t)gelu_exact(v.z); o[3] = (bf16_t)gelu_exact(v.w);
    *(bf16x4*)(g + (size_t)idx * 4) = o;
}

// ---------- fused GEMM: BM=64, BN=256, BK=64 ----------
__device__ __forceinline__ void gl_lds16(const void* g, void* l) {
    __builtin_amdgcn_global_load_lds(
        (const __attribute__((address_space(1))) unsigned int*)(uintptr_t)g,
        (__attribute__((address_space(3))) unsigned int*)(uintptr_t)l, 16, 0, 0);
}

__device__ __forceinline__ uint64_t pack4bf(float a, float b, float c, float d) {
    union { bf16_t h[4]; uint64_t q; } u;
    u.h[0] = (bf16_t)a; u.h[1] = (bf16_t)b; u.h[2] = (bf16_t)c; u.h[3] = (bf16_t)d;
    return u.q;
}

// Uniform cubic B-spline: 8 bf16 bases of one feature as 16 bytes (lo,hi).
__device__ __forceinline__ void spline8(float x, float g0, float invh,
                                        uint64_t& lo, uint64_t& hi) {
    float u = (x - g0) * invh;
    float jf = floorf(u);
    int j = (int)jf;
    float f = u - jf;
    float f2 = f * f, f3 = f2 * f;
    float om = 1.0f - f, om2 = om * om;
    float w0 = om2 * om * (1.0f / 6.0f);
    float w3 = f3 * (1.0f / 6.0f);
    float w1 = fmaf(0.5f, f3, 2.0f / 3.0f) - f2;
    float w2 = 1.0f - w0 - w1 - w3;       // partition of unity (exact identity)
    uint64_t W64 = pack4bf(w0, w1, w2, w3);
    if (!(u >= 0.0f && u < 11.0f)) W64 = 0;
    int sh = (j - 3) * 16;                // bit pos of w0 in the 128-bit window
    if (sh >= 0) {
        int s = sh & 63;
        uint64_t loW = W64 << s;
        uint64_t hiW = s ? (W64 >> (64 - s)) : 0ull;
        lo = (sh < 64) ? loW : 0ull;
        hi = (sh < 64) ? hiW : loW;
    } else {
        lo = W64 >> (-sh);
        hi = 0ull;
    }
}

// LDS layout: row stride 64 elem (128 B); physical 16B-chunk = logical ^ (row&7).
__device__ __forceinline__ void mfma_tile(const bf16_t* __restrict__ Ar0,
                                          const bf16_t* __restrict__ Ar1,
                                          const bf16_t* __restrict__ Br0,
                                          const bf16_t* __restrict__ Br1,
                                          f32x4 (&acc)[4][4]) {
#pragma unroll
    for (int kk = 0; kk < 2; kk++) {
        const bf16_t* Ar = kk ? Ar1 : Ar0;
        const bf16_t* Br = kk ? Br1 : Br0;
        bf16x8 af[4], bfr[4];
#pragma unroll
        for (int i = 0; i < 4; i++) af[i] = *(const bf16x8*)(Ar + i * 16 * 64);
#pragma unroll
        for (int j = 0; j < 4; j++) bfr[j] = *(const bf16x8*)(Br + j * 16 * 64);
#pragma unroll
        for (int i = 0; i < 4; i++)
#pragma unroll
            for (int j = 0; j < 4; j++)
                acc[i][j] = __builtin_amdgcn_mfma_f32_16x16x32_bf16(af[i], bfr[j], acc[i][j], 0, 0, 0);
    }
}

__global__ __launch_bounds__(256) void gemm_fused(
    const float* __restrict__ Y,       // [R,1024] f32 (raw layer input)
    const bf16_t* __restrict__ G,      // [R,1024] bf16 gelu(Y)
    const bf16_t* __restrict__ W,      // [1024,9216] packed bf16
    float* __restrict__ C,             // [R,1024] f32
    const float* __restrict__ gp,      // knot row (12 floats, uniform)
    int mmask, int mshift) {
    constexpr int K = KTOT, N = DIM;
    __shared__ __align__(16) bf16_t At[64 * 64];    // 8 KB
    __shared__ __align__(16) bf16_t Bt[256 * 64];   // 32 KB
    const int tid = threadIdx.x;
    const int l = tid & 63;
    const int w = tid >> 6;             // wave 0..3 tiles N (wm==0)
    const int bm = blockIdx.x & mmask, bn = blockIdx.x >> mshift;

    const float g0 = gp[0];
    const float invh = 1.0f / (gp[1] - gp[0]);

    // DMA slot for thread tid = LDS row tid>>3, physical chunk tid&7;
    // it must hold LOGICAL chunk (tid&7)^(row&7).
    const int lrow = tid >> 3;                      // 0..31
    const int lchk = (tid & 7) ^ (lrow & 7);
    const bf16_t* Gg = G + (size_t)(bm * 64 + lrow) * DIM + lchk * 8;
    const bf16_t* Bg = W + (size_t)(bn * 256 + lrow) * K + lchk * 8;
    bf16_t* Al = At + tid * 8;          // wave-uniform base + lane*16B
    bf16_t* Bl = Bt + tid * 8;

    // spline region: thread owns (rows lrow+32q (q<2), logical feature j0+(tid&7))
    const float* Yb = Y + (size_t)(bm * 64 + lrow) * DIM + (tid & 7);
    bf16_t* As = At + lrow * 64 + lchk * 8;

    f32x4 acc[4][4] = {};
    // fragment reads: A row (l&15)+16i; B row w*64+(l&15)+16j; row&7 = l&7.
    // logical chunk(kk) = (l>>4)+4kk; physical = logical ^ (l&7).
    const int cA = (l >> 4) ^ (l & 7);
    const bf16_t* Ar0 = At + (l & 15) * 64 + cA * 8;
    const bf16_t* Ar1 = At + (l & 15) * 64 + (cA ^ 4) * 8;
    const bf16_t* Br0 = Bt + (w * 64 + (l & 15)) * 64 + cA * 8;
    const bf16_t* Br1 = Bt + (w * 64 + (l & 15)) * 64 + (cA ^ 4) * 8;

    // ---- gelu region: K = [0, 1024) ----
    for (int k0 = 0; k0 < DIM; k0 += 64) {
#pragma unroll
        for (int q = 0; q < 2; q++)
            gl_lds16(Gg + (size_t)q * 32 * DIM + k0, Al + q * 2048);
#pragma unroll
        for (int q = 0; q < 8; q++)
            gl_lds16(Bg + (size_t)q * 32 * K + k0, Bl + q * 2048);
        asm volatile("s_waitcnt vmcnt(0)" ::: "memory");
        __syncthreads();
        mfma_tile(Ar0, Ar1, Br0, Br1, acc);
        __syncthreads();
    }

    // ---- spline region: K = [1024, 9216) ----
    float ycur[2], ynext[2];
#pragma unroll
    for (int q = 0; q < 2; q++) ycur[q] = Yb[(size_t)q * 32 * DIM];

    for (int k0 = DIM; k0 < K; k0 += 64) {
        const int j0 = (k0 - DIM) >> 3;
        const bool more = (k0 + 64) < K;
        if (more) {
#pragma unroll
            for (int q = 0; q < 2; q++) ynext[q] = Yb[(size_t)q * 32 * DIM + j0 + 8];
        }
#pragma unroll
        for (int q = 0; q < 8; q++)
            gl_lds16(Bg + (size_t)q * 32 * K + k0, Bl + q * 2048);
        // compute this iter's bases from prefetched ycur (no global dependency)
#pragma unroll
        for (int q = 0; q < 2; q++) {
            uint64_t lo, hi;
            spline8(ycur[q], g0, invh, lo, hi);
            union { uint64_t u[2]; uint4 v; } ov;
            ov.u[0] = lo; ov.u[1] = hi;
            *(uint4*)(As + q * 32 * 64) = ov.v;
        }
        asm volatile("s_waitcnt vmcnt(0)" ::: "memory");
        __syncthreads();
        mfma_tile(Ar0, Ar1, Br0, Br1, acc);
        __syncthreads();
        if (more) {
#pragma unroll
            for (int q = 0; q < 2; q++) ycur[q] = ynext[q];
        }
    }

    const int r0 = bm * 64 + (l >> 4) * 4;
    const int c0 = bn * 256 + w * 64 + (l & 15);
#pragma unroll
    for (int i = 0; i < 4; i++)
#pragma unroll
        for (int j = 0; j < 4; j++)
#pragma unroll
            for (int r = 0; r < 4; r++)
                C[(size_t)(r0 + i * 16 + r) * N + c0 + j * 16] = acc[i][j][r];
}

// ---------- LayerNorm + PReLU -> y (f32) + gelu(y) (bf16) ----------
__global__ void ln_mid(const float* __restrict__ h, const float* __restrict__ g_ln,
                       const float* __restrict__ b_ln, const float* __restrict__ pa,
                       float* __restrict__ y, bf16_t* __restrict__ yg) {
    const int row = blockIdx.x, tid = threadIdx.x;
    const int w = tid >> 6, l = tid & 63;
    f32x4 v = *(const f32x4*)(h + (size_t)row * DIM + tid * 4);
    float s = v[0] + v[1] + v[2] + v[3];
    float q = v[0] * v[0] + v[1] * v[1] + v[2] * v[2] + v[3] * v[3];
#pragma unroll
    for (int o = 32; o > 0; o >>= 1) { s += __shfl_xor(s, o); q += __shfl_xor(q, o); }
    __shared__ float rs[4], rq[4];
    if (l == 0) { rs[w] = s; rq[w] = q; }
    __syncthreads();
    s = rs[0] + rs[1] + rs[2] + rs[3];
    q = rq[0] + rq[1] + rq[2] + rq[3];
    float mean = s * (1.0f / DIM);
    float var = q * (1.0f / DIM) - mean * mean;
    float rstd = rsqrtf(var + LN_EPS);
    float a = pa[0];
    f32x4 o4;
    bf16x4 g4;
#pragma unroll
    for (int c = 0; c < 4; c++) {
        int col = tid * 4 + c;
        float yv = (v[c] - mean) * rstd * g_ln[col] + b_ln[col];
        yv = (yv >= 0.0f) ? yv : a * yv;
        o4[c] = yv;
        g4[c] = (bf16_t)gelu_exact(yv);
    }
    *(f32x4*)(y + (size_t)row * DIM + tid * 4) = o4;
    *(bf16x4*)(yg + (size_t)row * DIM + tid * 4) = g4;
}

// ---------- final LayerNorm + PReLU -> f32 out ----------
__global__ void ln_out(const float* __restrict__ h, const float* __restrict__ g_ln,
                       const float* __restrict__ b_ln, const float* __restrict__ pa,
                       float* __restrict__ out) {
    const int row = blockIdx.x, tid = threadIdx.x;
    const int w = tid >> 6, l = tid & 63;
    f32x4 v = *(const f32x4*)(h + (size_t)row * DIM + tid * 4);
    float s = v[0] + v[1] + v[2] + v[3];
    float q = v[0] * v[0] + v[1] * v[1] + v[2] * v[2] + v[3] * v[3];
#pragma unroll
    for (int o = 32; o > 0; o >>= 1) { s += __shfl_xor(s, o); q += __shfl_xor(q, o); }
    __shared__ float rs[4], rq[4];
    if (l == 0) { rs[w] = s; rq[w] = q; }
    __syncthreads();
    s = rs[0] + rs[1] + rs[2] + rs[3];
    q = rq[0] + rq[1] + rq[2] + rq[3];
    float mean = s * (1.0f / DIM);
    float var = q * (1.0f / DIM) - mean * mean;
    float rstd = rsqrtf(var + LN_EPS);
    float a = pa[0];
    f32x4 o4;
#pragma unroll
    for (int c = 0; c < 4; c++) {
        int col = tid * 4 + c;
        float yv = (v[c] - mean) * rstd * g_ln[col] + b_ln[col];
        o4[c] = (yv >= 0.0f) ? yv : a * yv;
    }
    *(f32x4*)(out + (size_t)row * DIM + tid * 4) = o4;
}

// ---------- launch ----------
extern "C" void kernel_launch(void* const* d_in, const int* in_sizes, int n_in,
                              void* d_out, int out_size, void* d_ws, size_t ws_size,
                              hipStream_t stream) {
    const float* x    = (const float*)d_in[0];
    const float* bw   = (const float*)d_in[1];
    const float* sw   = (const float*)d_in[2];
    const float* ln_g = (const float*)d_in[3];
    const float* ln_b = (const float*)d_in[4];
    const float* pa   = (const float*)d_in[5];
    const float* grid = (const float*)d_in[6];
    float* out = (float*)d_out;

    const size_t wbytes = (size_t)2 * DIM * KTOT * sizeof(bf16_t);   // 37.75 MB
    int R = 8192;
    while (R > 128 && wbytes + (size_t)R * DIM * 10 > ws_size) R >>= 1;
    int mtiles = R / 64;                 // BM = 64
    int mshift = 0; while ((1 << mshift) < mtiles) mshift++;
    int mmask = mtiles - 1;

    char* wsc = (char*)d_ws;
    bf16_t* Wbuf = (bf16_t*)wsc;
    bf16_t* ygel = (bf16_t*)(wsc + wbytes);
    float*  ybuf = (float*)(wsc + wbytes + (size_t)R * DIM * 2);
    float*  hbuf = (float*)(wsc + wbytes + (size_t)R * DIM * 6);

    pack_w<<<(2 * DIM * DIM) / 256, 256, 0, stream>>>(bw, sw, Wbuf);

    const int nslab = BATCH / R;
    for (int sidx = 0; sidx < nslab; sidx++) {
        const size_t row0 = (size_t)sidx * R;
        const float* x0 = x + row0 * DIM;
        // layer 0
        prep_gelu<<<R * DIM / 1024, 256, 0, stream>>>(x0, ygel);
        gemm_fused<<<mtiles * 4, 256, 0, stream>>>(x0, ygel, Wbuf, hbuf,
                                                   grid, mmask, mshift);
        ln_mid<<<R, 256, 0, stream>>>(hbuf, ln_g, ln_b, pa, ybuf, ygel);
        // layer 1
        gemm_fused<<<mtiles * 4, 256, 0, stream>>>(ybuf, ygel, Wbuf + (size_t)DIM * KTOT, hbuf,
                                                   grid + DIM * NKNOT, mmask, mshift);
        ln_out<<<R, 256, 0, stream>>>(hbuf, ln_g + DIM, ln_b + DIM, pa + 1, out + row0 * DIM);
    }
}